// Round 4
// baseline (452.788 us; speedup 1.0000x reference)
//
#include <hip/hip_runtime.h>
#include <hip/hip_bf16.h>
#include <math.h>

// AdaptGNN: B=8, N=2048, D=H=128, 3 layers.
// R8: agg rewritten as barrier-free attn-style kernel (m214 port):
//  - 32x32x16 MFMA, swapped S-phase (S^T = mfma(T_frag, tP_frag)) so each
//    lane holds S'[p=lane&31][q-rows] -> pack bf16 + __shfl_xor(32) half-swap
//    rebuilds the O-phase A-fragment IN REGISTERS (no Spm, no barrier).
//  - ew (the only p,q-indexed tensor) staged per-wave in private LDS:
//    coalesced float4 load -> swizzled write -> transposed read. Wave-local.
//  - Each wave owns 32 p-rows x q-tiles (qt = 4i+wq); t/tT fragments read
//    directly from L2 (batch pinned per XCD via blockIdx.x=batch).
//  - ZERO barriers in the main loop; 5-barrier LDS reduction at the end
//    merges the 4 wq partial accumulators.

typedef __attribute__((ext_vector_type(8)))  short bf16x8;
typedef __attribute__((ext_vector_type(4)))  short bf16x4;
typedef __attribute__((ext_vector_type(4)))  float f32x4;
typedef __attribute__((ext_vector_type(16))) float f32x16;

static constexpr int kB = 8, kN = 2048, kH = 128;

static __device__ __forceinline__ ushort bf16bits(float f) {
    __hip_bfloat16 hb = __float2bfloat16(f);
    return *reinterpret_cast<ushort*>(&hb);
}
static __device__ __forceinline__ unsigned pk2(float lo, float hi) {
    return (unsigned)bf16bits(lo) | ((unsigned)bf16bits(hi) << 16);
}

// ---------------- x -> bf16 ----------------
__global__ __launch_bounds__(256) void cvt_bf16_kernel(
    const float* __restrict__ src, ushort* __restrict__ dst, int n4)
{
    int i = blockIdx.x * 256 + threadIdx.x;
    if (i >= n4) return;
    float4 v = ((const float4*)src)[i];
    bf16x4 o;
    o[0] = (short)bf16bits(v.x); o[1] = (short)bf16bits(v.y);
    o[2] = (short)bf16bits(v.z); o[3] = (short)bf16bits(v.w);
    ((bf16x4*)dst)[i] = o;
}

// WT[l][c][d] = bf16(W_l[d][c]) — all 3 layers in one launch
__global__ __launch_bounds__(256) void cvt_wT_kernel(
    const float* __restrict__ W0, const float* __restrict__ W1,
    const float* __restrict__ W2, ushort* __restrict__ WT)
{
    const float* W = blockIdx.y == 0 ? W0 : (blockIdx.y == 1 ? W1 : W2);
    int i = blockIdx.x * 256 + threadIdx.x;  // 0..16383
    int d = i >> 7, c = i & 127;
    WT[(size_t)blockIdx.y * kH * kH + c * kH + d] = bf16bits(W[d * kH + c]);
}

// ---------------- linear (bf16 MFMA) + row-norm + transpose-out ----------------
// 64 rows/block (one batch slice), 256 thr = 4 waves (2r x 2c).
// Outputs: t16[b][q][d], tT16[b][d][q], invn[b][q].
__global__ __launch_bounds__(256) void linear_tr_kernel(
    const ushort* __restrict__ h16, const ushort* __restrict__ WT,
    const float* __restrict__ bias, ushort* __restrict__ t16,
    ushort* __restrict__ tT16, float* __restrict__ invn)
{
    __shared__ float ssb[64][2];
    __shared__ ushort tr[128 * 72];  // [c][p_local], stride 144B (odd-16B rotate)

    const int tid = threadIdx.x, lane = tid & 63, wid = tid >> 6;
    const int wr = wid >> 1, wc = wid & 1, quad = lane >> 4, l16 = lane & 15;
    const int rowbase = blockIdx.x * 64;           // global BN row
    const int b = rowbase / kN, q0 = rowbase % kN; // batch / in-batch row

    f32x4 acc[2][4];
#pragma unroll
    for (int i = 0; i < 2; ++i)
#pragma unroll
        for (int ct = 0; ct < 4; ++ct) acc[i][ct] = (f32x4){0.f, 0.f, 0.f, 0.f};

#pragma unroll
    for (int k = 0; k < 4; ++k) {
        bf16x8 Af[2], Bf[4];
#pragma unroll
        for (int i = 0; i < 2; ++i)
            Af[i] = *(const bf16x8*)&h16[(size_t)(rowbase + wr * 32 + i * 16 + l16) * kH + k * 32 + quad * 8];
#pragma unroll
        for (int ct = 0; ct < 4; ++ct)
            Bf[ct] = *(const bf16x8*)&WT[(size_t)(wc * 64 + ct * 16 + l16) * kH + k * 32 + quad * 8];
#pragma unroll
        for (int i = 0; i < 2; ++i)
#pragma unroll
            for (int ct = 0; ct < 4; ++ct)
                acc[i][ct] = __builtin_amdgcn_mfma_f32_16x16x32_bf16(Af[i], Bf[ct], acc[i][ct], 0, 0, 0);
    }

    float bsr[4];
#pragma unroll
    for (int ct = 0; ct < 4; ++ct) bsr[ct] = bias[wc * 64 + ct * 16 + l16];

    f32x4 ss[2] = {(f32x4){0,0,0,0}, (f32x4){0,0,0,0}};
#pragma unroll
    for (int i = 0; i < 2; ++i)
#pragma unroll
        for (int ct = 0; ct < 4; ++ct)
#pragma unroll
            for (int r = 0; r < 4; ++r) {
                float v = acc[i][ct][r] + bsr[ct];
                acc[i][ct][r] = v;
                ss[i][r] += v * v;
            }
#pragma unroll
    for (int step = 1; step < 16; step <<= 1)
#pragma unroll
        for (int i = 0; i < 2; ++i)
#pragma unroll
            for (int r = 0; r < 4; ++r) ss[i][r] += __shfl_xor(ss[i][r], step);

    if (l16 == 0)
#pragma unroll
        for (int i = 0; i < 2; ++i)
#pragma unroll
            for (int r = 0; r < 4; ++r)
                ssb[wr * 32 + i * 16 + quad * 4 + r][wc] = ss[i][r];
    __syncthreads();
    if (tid < 64) {
        float s2 = ssb[tid][0] + ssb[tid][1];
        invn[rowbase + tid] = 1.f / fmaxf(sqrtf(s2), 1e-12f);
    }

    // t16 stores + tr LDS (transposed) writes
#pragma unroll
    for (int i = 0; i < 2; ++i)
#pragma unroll
        for (int ct = 0; ct < 4; ++ct)
#pragma unroll
            for (int r = 0; r < 4; ++r) {
                const int pl = wr * 32 + i * 16 + quad * 4 + r;
                const int c = wc * 64 + ct * 16 + l16;
                ushort bits = bf16bits(acc[i][ct][r]);
                t16[(size_t)(rowbase + pl) * kH + c] = bits;
                tr[c * 72 + pl] = bits;
            }
    __syncthreads();

    // coalesced tT writeout: 128 c-rows x 64 q
    ushort* tTb = tT16 + (size_t)b * kH * kN;
#pragma unroll
    for (int it = 0; it < 4; ++it) {
        int idx = tid + 256 * it;           // 0..1023
        int c = idx >> 3, ch = idx & 7;
        bf16x8 v = *(const bf16x8*)&tr[c * 72 + ch * 8];
        *(bf16x8*)&tTb[(size_t)c * kN + q0 + ch * 8] = v;
    }
}

// ---------------- barrier-free fused aggregation ----------------
// 512 thr = 8 waves (wp = wid>>2 in {0,1}: 32 p-rows each; wq = wid&3:
// q-tile partition qt = 4i+wq). grid (8 batches, 32 p-blocks of 64).
__global__ __launch_bounds__(512, 2) void agg_kernel(
    const ushort* __restrict__ t, const ushort* __restrict__ tT,
    const float* __restrict__ invn, const float* __restrict__ ew,
    ushort* __restrict__ hout, float* __restrict__ fout, int last)
{
    __shared__ char lds[65536];  // 8 x 8KB wave-private ew tiles; epilogue reuses [0,32K)

    const int b = blockIdx.x, pbase = blockIdx.y * 64;
    const int tid = threadIdx.x, lane = tid & 63, wid = tid >> 6;
    const int wp = wid >> 2, wq = wid & 3;
    const int l31 = lane & 31, h = lane >> 5;

    const ushort* tb  = t  + (size_t)b * kN * kH;
    const ushort* tTb = tT + (size_t)b * kH * kN;
    const float*  ewb = ew + (size_t)b * kN * kN;
    const float*  invb = invn + b * kN;

    char* myEw = lds + wid * 8192;      // [32 p-rows][64 q] f32, 256B rows, XOR-swizzled
    const int pbg = pbase + wp * 32;

    // tP fragments: this wave's 32 p-rows of t, as B-operand of swapped S.
    // B[k=d][n=p]: lane n=l31, k-chunk = 8h; mfma m covers d=16m..16m+15.
    bf16x8 tP[8];
#pragma unroll
    for (int m = 0; m < 8; ++m)
        tP[m] = *(const bf16x8*)&tb[(size_t)(pbg + l31) * kH + m * 16 + h * 8];

    f32x16 oacc[4];
#pragma unroll
    for (int ct = 0; ct < 4; ++ct)
#pragma unroll
        for (int r = 0; r < 16; ++r) oacc[ct][r] = 0.f;

    // ew staging lane map: float4 per lane, 4 rows per pass
    const int sQ = (lane & 15) * 4;   // q offset (floats)
    const int sR = lane >> 4;         // row sub 0..3

    // prefetch ew for tile 0 (T14 issue-early)
    f32x4 eC[8]; f32x4 iqC;
    {
        const int qb = wq * 64;
        iqC = *(const f32x4*)&invb[qb + sQ];
#pragma unroll
        for (int j = 0; j < 8; ++j)
            eC[j] = *(const f32x4*)&ewb[(size_t)(pbg + 4 * j + sR) * kN + qb + sQ];
    }

    // scale S by (ew*invQ), pack to bf16, half-swap -> 2 A-frags (k=16 each)
    auto buildFrags = [&](const f32x16 s, int st, bf16x8* out2) {
        f32x4 ef[4];
#pragma unroll
        for (int g = 0; g < 4; ++g)
            ef[g] = *(const f32x4*)&myEw[l31 * 256 +
                     ((128 * st + 32 * g + 16 * h) ^ ((l31 & 15) << 4))];
        float sv[16];
#pragma unroll
        for (int r = 0; r < 16; ++r) sv[r] = s[r] * ef[r >> 2][r & 3];
#pragma unroll
        for (int kk = 0; kk < 2; ++kk) {
            const int e0 = kk * 8;
            // C-reg r <-> q-row (r&3)+8*(r>>2)+4h (+32*st). Low lanes keep
            // rows 0-3 (kk=0)/8-11 via regs, fetch 4-7/12-15 from lane+32.
            unsigned a0 = pk2(sv[e0 + 0], sv[e0 + 1]);
            unsigned a1 = pk2(sv[e0 + 2], sv[e0 + 3]);
            unsigned b0 = pk2(sv[e0 + 4], sv[e0 + 5]);
            unsigned b1 = pk2(sv[e0 + 6], sv[e0 + 7]);
            const unsigned ta0 = (unsigned)__shfl_xor((int)a0, 32);
            const unsigned ta1 = (unsigned)__shfl_xor((int)a1, 32);
            const unsigned tb0 = (unsigned)__shfl_xor((int)b0, 32);
            const unsigned tb1 = (unsigned)__shfl_xor((int)b1, 32);
            union { unsigned u[4]; bf16x8 v; } U;
            U.u[0] = h ? tb0 : a0;   // q-pair (8h+0, 8h+1)
            U.u[1] = h ? tb1 : a1;   // q-pair (8h+2, 8h+3)
            U.u[2] = h ? b0  : ta0;  // q-pair (8h+4, 8h+5)
            U.u[3] = h ? b1  : ta1;  // q-pair (8h+6, 8h+7)
            out2[kk] = U.v;
        }
    };

    for (int i = 0; i < 8; ++i) {
        const int qb = (4 * i + wq) * 64;

        // publish ew tile (fold invQ) into wave-private LDS (no barrier)
#pragma unroll
        for (int j = 0; j < 8; ++j) {
            const int row = 4 * j + sR;
            f32x4 e = eC[j] * iqC;
            *(f32x4*)&myEw[row * 256 + ((sQ * 4) ^ ((row & 15) << 4))] = e;
        }

        // S-phase (swapped): sN[q][p] = sum_d t[q][d]*t[p][d]
        f32x16 s0, s1;
#pragma unroll
        for (int r = 0; r < 16; ++r) { s0[r] = 0.f; s1[r] = 0.f; }
#pragma unroll
        for (int m = 0; m < 8; ++m) {
            bf16x8 a0 = *(const bf16x8*)&tb[(size_t)(qb + l31) * kH + m * 16 + h * 8];
            bf16x8 a1 = *(const bf16x8*)&tb[(size_t)(qb + 32 + l31) * kH + m * 16 + h * 8];
            s0 = __builtin_amdgcn_mfma_f32_32x32x16_bf16(a0, tP[m], s0, 0, 0, 0);
            s1 = __builtin_amdgcn_mfma_f32_32x32x16_bf16(a1, tP[m], s1, 0, 0, 0);
        }

        bf16x8 aw[4];
        buildFrags(s0, 0, &aw[0]);
        buildFrags(s1, 1, &aw[2]);

        // prefetch next tile's ew while O-phase runs (in-flight across it)
        if (i < 7) {
            const int qb2 = (4 * (i + 1) + wq) * 64;
            iqC = *(const f32x4*)&invb[qb2 + sQ];
#pragma unroll
            for (int j = 0; j < 8; ++j)
                eC[j] = *(const f32x4*)&ewb[(size_t)(pbg + 4 * j + sR) * kN + qb2 + sQ];
        }

        // O-phase: oacc[p][c] += S'[32p x 64q] @ t[64q x 128c]
        // B[k=q][n=c] from tT[c][q] (L2-resident)
#pragma unroll
        for (int kkt = 0; kkt < 4; ++kkt) {
#pragma unroll
            for (int ct = 0; ct < 4; ++ct) {
                bf16x8 Bf = *(const bf16x8*)&tTb[(size_t)(32 * ct + l31) * kN + qb + 16 * kkt + 8 * h];
                oacc[ct] = __builtin_amdgcn_mfma_f32_32x32x16_bf16(aw[kkt], Bf, oacc[ct], 0, 0, 0);
            }
        }
    }

    // ---- epilogue: reduce 4 wq partials in LDS, scale by invP, store ----
    __syncthreads();
    float* OL = (float*)lds;   // [64][128] f32 = 32 KB
#pragma unroll
    for (int w = 0; w < 4; ++w) {
        if (wq == w) {
#pragma unroll
            for (int ct = 0; ct < 4; ++ct)
#pragma unroll
                for (int r = 0; r < 16; ++r) {
                    const int pl = wp * 32 + (r & 3) + 8 * (r >> 2) + 4 * h;
                    const int idx = pl * 128 + 32 * ct + l31;
                    if (w == 0) OL[idx] = oacc[ct][r];
                    else        OL[idx] += oacc[ct][r];
                }
        }
        __syncthreads();
    }

    {
        const int p = tid >> 3, cb = (tid & 7) * 16;
        const float ip = invb[pbase + p];
        const size_t gbase = (size_t)b * kN * kH + (size_t)(pbase + p) * kH + cb;
        if (!last) {
#pragma unroll
            for (int u = 0; u < 2; ++u) {
                bf16x8 o;
#pragma unroll
                for (int k = 0; k < 8; ++k)
                    o[k] = (short)bf16bits(fmaxf(OL[p * 128 + cb + u * 8 + k] * ip, 0.f));
                *(bf16x8*)&hout[gbase + u * 8] = o;
            }
        } else {
#pragma unroll
            for (int u = 0; u < 4; ++u) {
                f32x4 o;
#pragma unroll
                for (int k = 0; k < 4; ++k)
                    o[k] = OL[p * 128 + cb + u * 4 + k] * ip;
                *(f32x4*)&fout[gbase + u * 4] = o;
            }
        }
    }
}

extern "C" void kernel_launch(void* const* d_in, const int* in_sizes, int n_in,
                              void* d_out, int out_size, void* d_ws, size_t ws_size,
                              hipStream_t stream) {
    const float* x  = (const float*)d_in[0];
    const float* ew = (const float*)d_in[1];
    const float* W0 = (const float*)d_in[2];
    const float* b0 = (const float*)d_in[3];
    const float* W1 = (const float*)d_in[4];
    const float* b1 = (const float*)d_in[5];
    const float* W2 = (const float*)d_in[6];
    const float* b2 = (const float*)d_in[7];
    const float* bias[3] = {b0, b1, b2};

    const size_t nBNH = (size_t)kB * kN * kH;  // 2M
    ushort* h16  = (ushort*)d_ws;               // [B,N,H] bf16 (x, then relu h)
    ushort* t16  = h16 + nBNH;                  // [B,N,H] bf16 post-linear
    ushort* tT16 = t16 + nBNH;                  // [B,H,N] bf16 transposed
    float*  invn = (float*)(tT16 + nBNH);       // [B,N]
    ushort* WT   = (ushort*)(invn + (size_t)kB * kN);  // 3 x [H,D] bf16
    float*  out  = (float*)d_out;

    cvt_bf16_kernel<<<(int)(nBNH / 4 + 255) / 256, 256, 0, stream>>>(x, h16, (int)(nBNH / 4));
    cvt_wT_kernel<<<dim3(64, 3), 256, 0, stream>>>(W0, W1, W2, WT);

    for (int layer = 0; layer < 3; ++layer) {
        linear_tr_kernel<<<kB * kN / 64, 256, 0, stream>>>(
            h16, WT + (size_t)layer * kH * kH, bias[layer], t16, tT16, invn);
        agg_kernel<<<dim3(kB, kN / 64), 512, 0, stream>>>(
            t16, tT16, invn, ew, h16, out, layer == 2 ? 1 : 0);
    }
}

// Round 5
// 312.622 us; speedup vs baseline: 1.4484x; 1.4484x over previous
//
#include <hip/hip_runtime.h>
#include <hip/hip_bf16.h>
#include <math.h>

// AdaptGNN: B=8, N=2048, D=H=128, 3 layers.
// R9 = R8's in-register S'->O handoff (validated) + coalesced LDS staging
// for ALL MFMA fragments (R8's scattered 32-lines-per-instr global frag
// loads were TA-serialization: MfmaUtil 5.6%, VALU 5%, HBM 8% - all idle).
//  - q-tile 128, 16 iters, 2 barriers/iter, single-buffered tiles (96KB).
//  - S-phase A-frags from swizzled TQ[128q][128d]; O-phase B-frags from
//    swizzled TT[128c][128q]; tP held in regs (one-time scattered load).
//  - ew: wave-private 32p x 32q f32 tile, transposed via LDS, no barrier.
//  - prefetch (rQ/rT/ew regs) issued right after barrier #1; counted vmcnt
//    keeps it in flight across the whole compute phase.

typedef __attribute__((ext_vector_type(8)))  short bf16x8;
typedef __attribute__((ext_vector_type(4)))  short bf16x4;
typedef __attribute__((ext_vector_type(4)))  float f32x4;
typedef __attribute__((ext_vector_type(16))) float f32x16;

static constexpr int kB = 8, kN = 2048, kH = 128;

static __device__ __forceinline__ ushort bf16bits(float f) {
    __hip_bfloat16 hb = __float2bfloat16(f);
    return *reinterpret_cast<ushort*>(&hb);
}
static __device__ __forceinline__ unsigned pk2(float lo, float hi) {
    return (unsigned)bf16bits(lo) | ((unsigned)bf16bits(hi) << 16);
}

// LDS-visibility fence + raw barrier: does NOT drain vmcnt (prefetch loads
// stay in flight; compiler inserts counted vmcnt at their uses).
#define LDS_BARRIER()                                          \
    do {                                                       \
        asm volatile("s_waitcnt lgkmcnt(0)" ::: "memory");     \
        __builtin_amdgcn_s_barrier();                          \
        __builtin_amdgcn_sched_barrier(0);                     \
    } while (0)

// ---------------- x -> bf16 ----------------
__global__ __launch_bounds__(256) void cvt_bf16_kernel(
    const float* __restrict__ src, ushort* __restrict__ dst, int n4)
{
    int i = blockIdx.x * 256 + threadIdx.x;
    if (i >= n4) return;
    float4 v = ((const float4*)src)[i];
    bf16x4 o;
    o[0] = (short)bf16bits(v.x); o[1] = (short)bf16bits(v.y);
    o[2] = (short)bf16bits(v.z); o[3] = (short)bf16bits(v.w);
    ((bf16x4*)dst)[i] = o;
}

// WT[l][c][d] = bf16(W_l[d][c]) — all 3 layers in one launch
__global__ __launch_bounds__(256) void cvt_wT_kernel(
    const float* __restrict__ W0, const float* __restrict__ W1,
    const float* __restrict__ W2, ushort* __restrict__ WT)
{
    const float* W = blockIdx.y == 0 ? W0 : (blockIdx.y == 1 ? W1 : W2);
    int i = blockIdx.x * 256 + threadIdx.x;  // 0..16383
    int d = i >> 7, c = i & 127;
    WT[(size_t)blockIdx.y * kH * kH + c * kH + d] = bf16bits(W[d * kH + c]);
}

// ---------------- linear (bf16 MFMA) + row-norm + transpose-out ----------------
__global__ __launch_bounds__(256) void linear_tr_kernel(
    const ushort* __restrict__ h16, const ushort* __restrict__ WT,
    const float* __restrict__ bias, ushort* __restrict__ t16,
    ushort* __restrict__ tT16, float* __restrict__ invn)
{
    __shared__ float ssb[64][2];
    __shared__ ushort tr[128 * 72];  // [c][p_local], stride 144B (odd-16B rotate)

    const int tid = threadIdx.x, lane = tid & 63, wid = tid >> 6;
    const int wr = wid >> 1, wc = wid & 1, quad = lane >> 4, l16 = lane & 15;
    const int rowbase = blockIdx.x * 64;           // global BN row
    const int b = rowbase / kN, q0 = rowbase % kN; // batch / in-batch row

    f32x4 acc[2][4];
#pragma unroll
    for (int i = 0; i < 2; ++i)
#pragma unroll
        for (int ct = 0; ct < 4; ++ct) acc[i][ct] = (f32x4){0.f, 0.f, 0.f, 0.f};

#pragma unroll
    for (int k = 0; k < 4; ++k) {
        bf16x8 Af[2], Bf[4];
#pragma unroll
        for (int i = 0; i < 2; ++i)
            Af[i] = *(const bf16x8*)&h16[(size_t)(rowbase + wr * 32 + i * 16 + l16) * kH + k * 32 + quad * 8];
#pragma unroll
        for (int ct = 0; ct < 4; ++ct)
            Bf[ct] = *(const bf16x8*)&WT[(size_t)(wc * 64 + ct * 16 + l16) * kH + k * 32 + quad * 8];
#pragma unroll
        for (int i = 0; i < 2; ++i)
#pragma unroll
            for (int ct = 0; ct < 4; ++ct)
                acc[i][ct] = __builtin_amdgcn_mfma_f32_16x16x32_bf16(Af[i], Bf[ct], acc[i][ct], 0, 0, 0);
    }

    float bsr[4];
#pragma unroll
    for (int ct = 0; ct < 4; ++ct) bsr[ct] = bias[wc * 64 + ct * 16 + l16];

    f32x4 ss[2] = {(f32x4){0,0,0,0}, (f32x4){0,0,0,0}};
#pragma unroll
    for (int i = 0; i < 2; ++i)
#pragma unroll
        for (int ct = 0; ct < 4; ++ct)
#pragma unroll
            for (int r = 0; r < 4; ++r) {
                float v = acc[i][ct][r] + bsr[ct];
                acc[i][ct][r] = v;
                ss[i][r] += v * v;
            }
#pragma unroll
    for (int step = 1; step < 16; step <<= 1)
#pragma unroll
        for (int i = 0; i < 2; ++i)
#pragma unroll
            for (int r = 0; r < 4; ++r) ss[i][r] += __shfl_xor(ss[i][r], step);

    if (l16 == 0)
#pragma unroll
        for (int i = 0; i < 2; ++i)
#pragma unroll
            for (int r = 0; r < 4; ++r)
                ssb[wr * 32 + i * 16 + quad * 4 + r][wc] = ss[i][r];
    __syncthreads();
    if (tid < 64) {
        float s2 = ssb[tid][0] + ssb[tid][1];
        invn[rowbase + tid] = 1.f / fmaxf(sqrtf(s2), 1e-12f);
    }

    // t16 stores + tr LDS (transposed) writes
#pragma unroll
    for (int i = 0; i < 2; ++i)
#pragma unroll
        for (int ct = 0; ct < 4; ++ct)
#pragma unroll
            for (int r = 0; r < 4; ++r) {
                const int pl = wr * 32 + i * 16 + quad * 4 + r;
                const int c = wc * 64 + ct * 16 + l16;
                ushort bits = bf16bits(acc[i][ct][r]);
                t16[(size_t)(rowbase + pl) * kH + c] = bits;
                tr[c * 72 + pl] = bits;
            }
    __syncthreads();

    // coalesced tT writeout: 128 c-rows x 64 q
    ushort* tTb = tT16 + (size_t)b * kH * kN;
#pragma unroll
    for (int it = 0; it < 4; ++it) {
        int idx = tid + 256 * it;           // 0..1023
        int c = idx >> 3, ch = idx & 7;
        bf16x8 v = *(const bf16x8*)&tr[c * 72 + ch * 8];
        *(bf16x8*)&tTb[(size_t)c * kN + q0 + ch * 8] = v;
    }
}

// ---------------- fused aggregation: LDS-staged frags + in-register S'->O ----------------
// 512 thr = 8 waves (wp = wid>>2: p 32-halves of the 64 p-block;
// wq = wid&3: q 32-quarters of the 128 q-tile). grid (8 batches, 32 p-blocks).
__global__ __launch_bounds__(512, 2) void agg_kernel(
    const ushort* __restrict__ t, const ushort* __restrict__ tT,
    const float* __restrict__ invn, const float* __restrict__ ew,
    ushort* __restrict__ hout, float* __restrict__ fout, int last)
{
    __shared__ char lds[98304];  // TQ 32K | TT 32K | ew 8x4K; epilogue reuses [0,32K)

    const int b = blockIdx.x, pbase = blockIdx.y * 64;
    const int tid = threadIdx.x, lane = tid & 63, wid = tid >> 6;
    const int wp = wid >> 2, wq = wid & 3;
    const int l31 = lane & 31, h = lane >> 5;

    const ushort* tb  = t  + (size_t)b * kN * kH;
    const ushort* tTb = tT + (size_t)b * kH * kN;
    const float*  ewb = ew + (size_t)b * kN * kN;
    const float*  invb = invn + b * kN;

    char* TQ   = lds;                         // [128 q][256B], swz ((q&15)<<4)
    char* TT   = lds + 32768;                 // [128 c][256B], swz ((c&15)<<4)
    char* myEw = lds + 65536 + wid * 4096;    // [32 p][128B] f32, swz ((p&7)<<4)

    const int pbg = pbase + wp * 32;

    // tP (B-operand of swapped S): one-time scattered load, held all kernel
    bf16x8 tP[8];
#pragma unroll
    for (int m = 0; m < 8; ++m)
        tP[m] = *(const bf16x8*)&tb[(size_t)(pbg + l31) * kH + m * 16 + h * 8];

    f32x16 oacc[4];
#pragma unroll
    for (int ct = 0; ct < 4; ++ct)
#pragma unroll
        for (int r = 0; r < 16; ++r) oacc[ct][r] = 0.f;

    // staging maps: TQ/TT 16 thr/row (16B chunks), 32 rows/pass x 4 passes
    const int sgRow = tid >> 4, sgCh = tid & 15;
    // ew map: 8 lanes/row (float4), 8 rows/pass x 4 passes (wave covers 32p x 32q)
    const int ewR = lane >> 3, ewQ = lane & 7;

    bf16x8 rQ[4], rT[4];
    f32x4 eC[4], iqC;

    auto prefetch = [&](int qb) {
#pragma unroll
        for (int j = 0; j < 4; ++j) {
            rQ[j] = *(const bf16x8*)&tb[(size_t)(qb + sgRow + 32 * j) * kH + sgCh * 8];
            rT[j] = *(const bf16x8*)&tTb[(size_t)(sgRow + 32 * j) * kN + qb + sgCh * 8];
        }
        iqC = *(const f32x4*)&invb[qb + wq * 32 + ewQ * 4];
#pragma unroll
        for (int j = 0; j < 4; ++j)
            eC[j] = *(const f32x4*)&ewb[(size_t)(pbg + 8 * j + ewR) * kN + qb + wq * 32 + ewQ * 4];
    };
    prefetch(0);

    // scale S'[32p x 32q] by (ew*invQ), pack bf16, half-swap -> 2 A-frags
    auto buildFrags = [&](const f32x16& s, bf16x8* out2) {
        f32x4 ef[4];
#pragma unroll
        for (int g = 0; g < 4; ++g)
            ef[g] = *(const f32x4*)&myEw[l31 * 128 + ((32 * g + 16 * h) ^ ((l31 & 7) << 4))];
        float sv[16];
#pragma unroll
        for (int r = 0; r < 16; ++r) sv[r] = s[r] * ef[r >> 2][r & 3];
#pragma unroll
        for (int kk = 0; kk < 2; ++kk) {
            const int e0 = kk * 8;
            unsigned a0 = pk2(sv[e0 + 0], sv[e0 + 1]);
            unsigned a1 = pk2(sv[e0 + 2], sv[e0 + 3]);
            unsigned b0 = pk2(sv[e0 + 4], sv[e0 + 5]);
            unsigned b1 = pk2(sv[e0 + 6], sv[e0 + 7]);
            const unsigned ta0 = (unsigned)__shfl_xor((int)a0, 32);
            const unsigned ta1 = (unsigned)__shfl_xor((int)a1, 32);
            const unsigned tb0 = (unsigned)__shfl_xor((int)b0, 32);
            const unsigned tb1 = (unsigned)__shfl_xor((int)b1, 32);
            union { unsigned u[4]; bf16x8 v; } U;
            U.u[0] = h ? tb0 : a0;   // q-pair (8h+0, 8h+1)
            U.u[1] = h ? tb1 : a1;   // q-pair (8h+2, 8h+3)
            U.u[2] = h ? b0  : ta0;  // q-pair (8h+4, 8h+5)
            U.u[3] = h ? b1  : ta1;  // q-pair (8h+6, 8h+7)
            out2[kk] = U.v;
        }
    };

    for (int it = 0; it < 16; ++it) {
        // ---- publish staged tile (single buffer) ----
#pragma unroll
        for (int j = 0; j < 4; ++j) {
            const int row = sgRow + 32 * j;
            const int swz = (row & 15) << 4;
            *(bf16x8*)&TQ[row * 256 + ((sgCh * 16) ^ swz)] = rQ[j];
            *(bf16x8*)&TT[row * 256 + ((sgCh * 16) ^ swz)] = rT[j];
        }
#pragma unroll
        for (int j = 0; j < 4; ++j) {
            const int row = 8 * j + ewR;
            f32x4 e = eC[j] * iqC;
            *(f32x4*)&myEw[row * 128 + ((ewQ * 16) ^ ((row & 7) << 4))] = e;
        }
        LDS_BARRIER();  // #1: tiles visible

        // ---- issue next tile's globals (in flight across whole compute) ----
        if (it < 15) prefetch((it + 1) * 128);

        // ---- S-phase: s[q=32(wq)][p=32(wp)] = tQ . tP^T over d=128 ----
        f32x16 s0;
#pragma unroll
        for (int r = 0; r < 16; ++r) s0[r] = 0.f;
        const int qrow = wq * 32 + l31;
        const int qswz = (qrow & 15) << 4;
#pragma unroll
        for (int m = 0; m < 8; ++m) {
            bf16x8 a = *(const bf16x8*)&TQ[qrow * 256 + ((m * 32 + 16 * h) ^ qswz)];
            s0 = __builtin_amdgcn_mfma_f32_32x32x16_bf16(a, tP[m], s0, 0, 0, 0);
        }

        bf16x8 aw[2];
        buildFrags(s0, aw);

        // ---- O-phase: oacc[p][c] += S'[32p x 32q] @ t[32q x 128c] ----
#pragma unroll
        for (int kkt = 0; kkt < 2; ++kkt) {
#pragma unroll
            for (int ct = 0; ct < 4; ++ct) {
                const int crow = 32 * ct + l31;
                bf16x8 Bf = *(const bf16x8*)&TT[crow * 256 +
                              ((wq * 64 + kkt * 32 + 16 * h) ^ ((crow & 15) << 4))];
                oacc[ct] = __builtin_amdgcn_mfma_f32_32x32x16_bf16(aw[kkt], Bf, oacc[ct], 0, 0, 0);
            }
        }
        LDS_BARRIER();  // #2: all reads of this tile done -> next publish safe
    }

    // ---- epilogue: reduce 4 wq partials in LDS, scale by invP, store ----
    __syncthreads();
    float* OL = (float*)lds;   // [64][128] f32 = 32 KB
#pragma unroll
    for (int w = 0; w < 4; ++w) {
        if (wq == w) {
#pragma unroll
            for (int ct = 0; ct < 4; ++ct)
#pragma unroll
                for (int r = 0; r < 16; ++r) {
                    const int pl = wp * 32 + (r & 3) + 8 * (r >> 2) + 4 * h;
                    const int idx = pl * 128 + 32 * ct + l31;
                    if (w == 0) OL[idx] = oacc[ct][r];
                    else        OL[idx] += oacc[ct][r];
                }
        }
        __syncthreads();
    }

    {
        const int p = tid >> 3, cb = (tid & 7) * 16;
        const float ip = invb[pbase + p];
        const size_t gbase = (size_t)b * kN * kH + (size_t)(pbase + p) * kH + cb;
        if (!last) {
#pragma unroll
            for (int u = 0; u < 2; ++u) {
                bf16x8 o;
#pragma unroll
                for (int k = 0; k < 8; ++k)
                    o[k] = (short)bf16bits(fmaxf(OL[p * 128 + cb + u * 8 + k] * ip, 0.f));
                *(bf16x8*)&hout[gbase + u * 8] = o;
            }
        } else {
#pragma unroll
            for (int u = 0; u < 4; ++u) {
                f32x4 o;
#pragma unroll
                for (int k = 0; k < 4; ++k)
                    o[k] = OL[p * 128 + cb + u * 4 + k] * ip;
                *(f32x4*)&fout[gbase + u * 4] = o;
            }
        }
    }
}

extern "C" void kernel_launch(void* const* d_in, const int* in_sizes, int n_in,
                              void* d_out, int out_size, void* d_ws, size_t ws_size,
                              hipStream_t stream) {
    const float* x  = (const float*)d_in[0];
    const float* ew = (const float*)d_in[1];
    const float* W0 = (const float*)d_in[2];
    const float* b0 = (const float*)d_in[3];
    const float* W1 = (const float*)d_in[4];
    const float* b1 = (const float*)d_in[5];
    const float* W2 = (const float*)d_in[6];
    const float* b2 = (const float*)d_in[7];
    const float* bias[3] = {b0, b1, b2};

    const size_t nBNH = (size_t)kB * kN * kH;  // 2M
    ushort* h16  = (ushort*)d_ws;               // [B,N,H] bf16 (x, then relu h)
    ushort* t16  = h16 + nBNH;                  // [B,N,H] bf16 post-linear
    ushort* tT16 = t16 + nBNH;                  // [B,H,N] bf16 transposed
    float*  invn = (float*)(tT16 + nBNH);       // [B,N]
    ushort* WT   = (ushort*)(invn + (size_t)kB * kN);  // 3 x [H,D] bf16
    float*  out  = (float*)d_out;

    cvt_bf16_kernel<<<(int)(nBNH / 4 + 255) / 256, 256, 0, stream>>>(x, h16, (int)(nBNH / 4));
    cvt_wT_kernel<<<dim3(64, 3), 256, 0, stream>>>(W0, W1, W2, WT);

    for (int layer = 0; layer < 3; ++layer) {
        linear_tr_kernel<<<kB * kN / 64, 256, 0, stream>>>(
            h16, WT + (size_t)layer * kH * kH, bias[layer], t16, tT16, invn);
        agg_kernel<<<dim3(kB, kN / 64), 512, 0, stream>>>(
            t16, tT16, invn, ew, h16, out, layer == 2 ? 1 : 0);
    }
}